// Round 3
// baseline (137.883 us; speedup 1.0000x reference)
//
#include <hip/hip_runtime.h>

// Point-transformer block. R16 = R15 (4 groups/block, 4 autonomous waves)
// with (a) __launch_bounds__(256,4): 128-VGPR budget. R15's (256,6) build
// landed at 40 VGPRs -- too few to keep the hoisted j-side a-table (32 VGPRs)
// and e-loop prefetch resident, so the compiler re-read LDS/weights in-loop.
// Occupancy is 16 waves/CU either way, so (256,4) costs no residency.
// (b) the two 'half' passes of phase 2 merged into one pass over cc handling
// all 4 i's: each weight dword loaded once per group (was twice), 12
// independent dot-chains of ILP. Per-pair op order unchanged (bit-identical).

typedef _Float16 h2 __attribute__((ext_vector_type(2)));
typedef _Float16 h8 __attribute__((ext_vector_type(8)));

#define AH_STRIDE 36    // a-table row stride in dwords (32 data + 4 pad)
#define MW1_OFF  256    // ws offset: mw1 pairs, [24][48] dwords
#define MW2_OFF 1408    // ws offset: mw2 pairs, [24][48] dwords

union H8U { h8 v; h2 p[4]; unsigned u[4]; };

__device__ __forceinline__ h2 pkrtz(float a, float b) {
    return __builtin_bit_cast(h2, __builtin_amdgcn_cvt_pkrtz(a, b));
}
__device__ __forceinline__ h2 uash2(unsigned u) {
    return __builtin_bit_cast(h2, u);
}
__device__ __forceinline__ h2 hmax2(h2 a, h2 b) {
    return __builtin_elementwise_max(a, b);   // v_pk_max_f16
}

#if __has_builtin(__builtin_amdgcn_fdot2)
__device__ __forceinline__ float dot2acc(h2 a, h2 b, float c) {
    return __builtin_amdgcn_fdot2(a, b, c, false);
}
#else
__device__ __forceinline__ float dot2acc(h2 a, h2 b, float c) {
    float d;
    asm("v_dot2_f32_f16 %0, %1, %2, %3"
        : "=v"(d)
        : "v"(__builtin_bit_cast(int, a)), "v"(__builtin_bit_cast(int, b)), "v"(c));
    return d;
}
#endif

// sum across the 16-lane DPP row via row_ror 1,2,4,8 (all lanes get total)
__device__ __forceinline__ float dpp_add16(float x) {
    float s = x;
    int t;
    t = __builtin_amdgcn_update_dpp(0, __builtin_bit_cast(int, s), 0x121, 0xf, 0xf, false);
    s += __builtin_bit_cast(float, t);
    t = __builtin_amdgcn_update_dpp(0, __builtin_bit_cast(int, s), 0x122, 0xf, 0xf, false);
    s += __builtin_bit_cast(float, t);
    t = __builtin_amdgcn_update_dpp(0, __builtin_bit_cast(int, s), 0x124, 0xf, 0xf, false);
    s += __builtin_bit_cast(float, t);
    t = __builtin_amdgcn_update_dpp(0, __builtin_bit_cast(int, s), 0x128, 0xf, 0xf, false);
    s += __builtin_bit_cast(float, t);
    return s;
}

// ---- pre-kernel: pack f16-pair weight tables into workspace ----
__global__ void wpack(const float* __restrict__ pw2, const float* __restrict__ aw1,
                      const float* __restrict__ ab1, const float* __restrict__ aw2,
                      const float* __restrict__ mw1, const float* __restrict__ mw2,
                      unsigned* __restrict__ ws) {
    const int t = threadIdx.x;
    const float L2E = 1.44269504f;
    if (blockIdx.x == 0) {
        if (t < 96) {
            const int hp = t & 31, c = t >> 5;
            ws[c*32+hp] = __builtin_bit_cast(unsigned, pkrtz(pw2[(2*hp)*3+c], pw2[(2*hp+1)*3+c]));
        } else if (t < 114) {
            const int idx = t - 96, r = idx / 6, gp = idx % 6;
            ws[96+r*6+gp] = __builtin_bit_cast(unsigned, pkrtz(aw1[r*12+2*gp], aw1[r*12+2*gp+1]));
        } else if (t < 120) {
            const int gp = t - 114;
            ws[114+gp] = __builtin_bit_cast(unsigned, pkrtz(ab1[2*gp], ab1[2*gp+1]));
        } else if (t < 138) {
            const int idx = t - 120, gp = idx / 3, c = idx % 3;
            ws[120+gp*3+c] = __builtin_bit_cast(unsigned,
                pkrtz(aw2[(2*gp)*3+c] * L2E, aw2[(2*gp+1)*3+c] * L2E));
        }
    }
    // mw1/mw2 pair tables: 1152 entries each
    const int idx = blockIdx.x * 256 + t;
    if (idx < 1152) {
        const int cp = idx / 48, o = idx % 48;
        ws[MW1_OFF + idx] = __builtin_bit_cast(unsigned,
            pkrtz(mw1[(2*cp)*48+o], mw1[(2*cp+1)*48+o]));
        ws[MW2_OFF + idx] = __builtin_bit_cast(unsigned,
            pkrtz(mw2[(2*cp)*48+o], mw2[(2*cp+1)*48+o]));
    }
}

struct SmWave {
    float q4[64], k4[64], v4[64];      // 768 B
    float sa[48], h1[48];              // 384 B
    unsigned a1h[16 * AH_STRIDE];      // 2304 B
    unsigned a2h[16 * AH_STRIDE];      // 2304 B
};                                     // 5760 B/wave, 16B-aligned members

__global__ __launch_bounds__(256, 4) void pt_main(
    const float* __restrict__ data,     // (BG, 16, 3)
    const float* __restrict__ wqkv,     // (3, 9)
    const float* __restrict__ pw1,      // (3, 64)
    const float* __restrict__ pb1,      // (64)
    const float* __restrict__ pb2,      // (3)
    const float* __restrict__ ab2,      // (3)
    const float* __restrict__ mb1,      // (48)
    const float* __restrict__ mb2,      // (48)
    const float* __restrict__ mw3,      // (48, 1)
    const float* __restrict__ mb3,      // (1)
    const unsigned* __restrict__ wsp,   // packed f16-pair weights
    float* __restrict__ out)            // (BG)
{
    __shared__ __attribute__((aligned(16))) SmWave sm[4];

    const int tid = threadIdx.x;
    const int w   = tid >> 6;           // wave id within block
    const int ln  = tid & 63;           // lane within wave
    const int g   = blockIdx.x * 4 + w; // group handled by this wave
    SmWave& S = sm[w];

    // single data[] load for both phase-1 stages (same point p for 1a & 1b)
    const int p  = ln & 15;
    const float x0 = data[g*48 + p*3 + 0];
    const float x1 = data[g*48 + p*3 + 1];
    const float x2 = data[g*48 + p*3 + 2];

    // ---- phase 1a: qkv (lanes 0..47), stride-4 layout ----
    if (ln < 48) {
        const int sec = ln >> 4;
        float* dst = (sec == 0) ? S.q4 : (sec == 1) ? S.k4 : S.v4;
        #pragma unroll
        for (int c = 0; c < 3; ++c) {
            dst[p*4+c] = fmaf(x0, wqkv[0*9 + sec*3 + c],
                         fmaf(x1, wqkv[1*9 + sec*3 + c],
                         x2 * wqkv[2*9 + sec*3 + c]));
        }
        dst[p*4+3] = 0.0f;
    }

    // ---- phase 1b: a-tables. lane -> point p, 16 hiddens at (ln>>4)*16 ----
    {
        const int qd = ln >> 4;
        const int hc = qd << 4;
        float s[16];
        #pragma unroll
        for (int c = 0; c < 16; ++c) {
            const int h = hc + c;
            s[c] = fmaf(x0, pw1[h], fmaf(x1, pw1[64+h], x2 * pw1[128+h]));
        }
        uint4 a1u0, a1u1, a2u0, a2u1;
        #pragma unroll
        for (int d = 0; d < 4; ++d) {
            const int c = d * 2;
            (&a1u0.x)[d] = __builtin_bit_cast(unsigned, pkrtz(s[c]   + pb1[hc+c],   s[c+1] + pb1[hc+c+1]));
            (&a1u1.x)[d] = __builtin_bit_cast(unsigned, pkrtz(s[8+c] + pb1[hc+8+c], s[9+c] + pb1[hc+9+c]));
            (&a2u0.x)[d] = __builtin_bit_cast(unsigned, pkrtz(s[c],   s[c+1]));
            (&a2u1.x)[d] = __builtin_bit_cast(unsigned, pkrtz(s[8+c], s[9+c]));
        }
        const int base = p * AH_STRIDE + (qd << 3);
        *(uint4*)&S.a1h[base]     = a1u0;
        *(uint4*)&S.a1h[base + 4] = a1u1;
        *(uint4*)&S.a2h[base]     = a2u0;
        *(uint4*)&S.a2h[base + 4] = a2u1;
    }
    __builtin_amdgcn_wave_barrier();   // order DS writes before phase-2 reads

    // ---- phase 2: 4 pairs per lane in ONE pass. j=ln&15, i = q+4s, s=0..3 ----
    const int j = p, q = ln >> 4;
    const float4 kv = *(const float4*)&S.k4[j*4];
    const float4 vv = *(const float4*)&S.v4[j*4];
    const h2 z2 = {(_Float16)0, (_Float16)0};
    const float L2E = 1.44269504f;
    const float mb_0 = ab2[0] * L2E, mb_1 = ab2[1] * L2E, mb_2 = ab2[2] * L2E;

    // hoist the j-side a-table (shared by all 4 pairs): 8 x b128
    H8U ajr[8];
    #pragma unroll
    for (int cc = 0; cc < 8; ++cc)
        ajr[cc].v = *(const h8*)&S.a2h[j * AH_STRIDE + cc*4];

    // e-accumulators: e[s][c] for i = q+4s
    float e[4][3];
    #pragma unroll
    for (int s = 0; s < 4; ++s) {
        e[s][0] = pb2[0]; e[s][1] = pb2[1]; e[s][2] = pb2[2];
    }

    #pragma unroll
    for (int cc = 0; cc < 8; ++cc) {
        H8U ai[4];
        #pragma unroll
        for (int s = 0; s < 4; ++s)
            ai[s].v = *(const h8*)&S.a1h[(q + 4*s) * AH_STRIDE + cc*4];
        #pragma unroll
        for (int m = 0; m < 4; ++m) {
            const int hp = cc*4 + m;
            const h2 w0 = uash2(wsp[0*32+hp]);
            const h2 w1 = uash2(wsp[1*32+hp]);
            const h2 w2 = uash2(wsp[2*32+hp]);
            #pragma unroll
            for (int s = 0; s < 4; ++s) {
                h2 r = hmax2(ai[s].p[m] - ajr[cc].p[m], z2);
                e[s][0] = dot2acc(r, w0, e[s][0]);
                e[s][1] = dot2acc(r, w1, e[s][1]);
                e[s][2] = dot2acc(r, w2, e[s][2]);
            }
        }
    }

    // vi / si for all 4 pairs (per-pair op order as before: (q-k)+e, v+e)
    float vi[4][3], si[4][3];
    #pragma unroll
    for (int s = 0; s < 4; ++s) {
        const float4 qv = *(const float4*)&S.q4[(q + 4*s)*4];
        vi[s][0] = vv.x + e[s][0]; vi[s][1] = vv.y + e[s][1]; vi[s][2] = vv.z + e[s][2];
        si[s][0] = qv.x - kv.x + e[s][0];
        si[s][1] = qv.y - kv.y + e[s][1];
        si[s][2] = qv.z - kv.z + e[s][2];
    }

    // attn-MLP in packed f16, all 4 pairs, weights loaded once
    h2 sx[4], sy[4], sz[4];
    #pragma unroll
    for (int s = 0; s < 4; ++s) {
        sx[s] = pkrtz(si[s][0], si[s][0]);
        sy[s] = pkrtz(si[s][1], si[s][1]);
        sz[s] = pkrtz(si[s][2], si[s][2]);
    }
    float mm[4][3];
    #pragma unroll
    for (int s = 0; s < 4; ++s) { mm[s][0] = mb_0; mm[s][1] = mb_1; mm[s][2] = mb_2; }

    #pragma unroll
    for (int gp = 0; gp < 6; ++gp) {
        const h2 b1p = uash2(wsp[114+gp]);
        const h2 u0 = uash2(wsp[96+0*6+gp]);
        const h2 u1 = uash2(wsp[96+1*6+gp]);
        const h2 u2 = uash2(wsp[96+2*6+gp]);
        const h2 v0 = uash2(wsp[120+gp*3+0]);
        const h2 v1 = uash2(wsp[120+gp*3+1]);
        const h2 v2 = uash2(wsp[120+gp*3+2]);
        #pragma unroll
        for (int s = 0; s < 4; ++s) {
            h2 acc = b1p;
            acc = __builtin_elementwise_fma(sx[s], u0, acc);
            acc = __builtin_elementwise_fma(sy[s], u1, acc);
            acc = __builtin_elementwise_fma(sz[s], u2, acc);
            h2 hh = hmax2(acc, z2);
            mm[s][0] = dot2acc(hh, v0, mm[s][0]);
            mm[s][1] = dot2acc(hh, v1, mm[s][1]);
            mm[s][2] = dot2acc(hh, v2, mm[s][2]);
        }
    }

    // softmax over j (DPP row sums; exponents already in log2 domain)
    float nsum[4][3], dsum[4][3];
    #pragma unroll
    for (int s = 0; s < 4; ++s) {
        #pragma unroll
        for (int c = 0; c < 3; ++c) {
            const float pp = __builtin_amdgcn_exp2f(mm[s][c]);
            nsum[s][c] = dpp_add16(pp * vi[s][c]);
            dsum[s][c] = dpp_add16(pp);
        }
    }

    if (j == 0) {
        #pragma unroll
        for (int s = 0; s < 4; ++s) {
            const int i = q + 4*s;
            S.sa[i*3+0] = nsum[s][0] * __builtin_amdgcn_rcpf(dsum[s][0]);
            S.sa[i*3+1] = nsum[s][1] * __builtin_amdgcn_rcpf(dsum[s][1]);
            S.sa[i*3+2] = nsum[s][2] * __builtin_amdgcn_rcpf(dsum[s][2]);
        }
    }
    __builtin_amdgcn_wave_barrier();   // s_sa writes before tail reads

    // ---- phase 3: MLP 48->48->48->1 (lanes 0..47), f16-pair weights ----
    if (ln < 48) {
        const int o = ln;
        float a0 = 0.f, a1 = 0.f;
        #pragma unroll
        for (int c = 0; c < 48; c += 4) {
            const float4 sa = *(const float4*)&S.sa[c];   // broadcast read
            const h2 pa = pkrtz(sa.x, sa.y);
            const h2 pb = pkrtz(sa.z, sa.w);
            a0 = dot2acc(pa, uash2(wsp[MW1_OFF + (c>>1)*48 + o]), a0);
            a1 = dot2acc(pb, uash2(wsp[MW1_OFF + ((c>>1)+1)*48 + o]), a1);
        }
        S.h1[o] = fmaxf(a0 + a1 + mb1[o], 0.0f);
        __builtin_amdgcn_wave_barrier();   // same-wave LDS handoff
        float b0 = 0.f, b1 = 0.f;
        #pragma unroll
        for (int c = 0; c < 48; c += 4) {
            const float4 hh = *(const float4*)&S.h1[c];
            const h2 pa = pkrtz(hh.x, hh.y);
            const h2 pb = pkrtz(hh.z, hh.w);
            b0 = dot2acc(pa, uash2(wsp[MW2_OFF + (c>>1)*48 + o]), b0);
            b1 = dot2acc(pb, uash2(wsp[MW2_OFF + ((c>>1)+1)*48 + o]), b1);
        }
        const float h2v = fmaxf(b0 + b1 + mb2[o], 0.0f);
        const float fv = h2v * mw3[o];
        const float r = dpp_add16(fv);     // row sums in lanes 0,16,32
        const int ri = __builtin_bit_cast(int, r);
        const float tot =
            __builtin_bit_cast(float, __builtin_amdgcn_readlane(ri, 0)) +
            __builtin_bit_cast(float, __builtin_amdgcn_readlane(ri, 16)) +
            __builtin_bit_cast(float, __builtin_amdgcn_readlane(ri, 32));
        if (o == 0) out[g] = tot + mb3[0];
    }
}

extern "C" void kernel_launch(void* const* d_in, const int* in_sizes, int n_in,
                              void* d_out, int out_size, void* d_ws, size_t ws_size,
                              hipStream_t stream) {
    const float* data = (const float*)d_in[1];
    unsigned* ws = (unsigned*)d_ws;
    const int groups = out_size;  // B*G = 16384

    wpack<<<5, 256, 0, stream>>>(
        (const float*)d_in[5],   // pw2
        (const float*)d_in[7],   // aw1
        (const float*)d_in[8],   // ab1
        (const float*)d_in[9],   // aw2
        (const float*)d_in[11],  // mw1
        (const float*)d_in[13],  // mw2
        ws);

    pt_main<<<groups / 4, 256, 0, stream>>>(
        data,
        (const float*)d_in[2],   // wqkv
        (const float*)d_in[3],   // pw1
        (const float*)d_in[4],   // pb1
        (const float*)d_in[6],   // pb2
        (const float*)d_in[10],  // ab2
        (const float*)d_in[12],  // mb1
        (const float*)d_in[14],  // mb2
        (const float*)d_in[15],  // mw3
        (const float*)d_in[16],  // mb3
        ws,
        (float*)d_out);
}

// Round 4
// 135.710 us; speedup vs baseline: 1.0160x; 1.0160x over previous
//
#include <hip/hip_runtime.h>

// Point-transformer block. R17 = R13's proven two-half phase-2 dataflow
// (bit-identical numerics, peak live set ~75 regs) in the 4-waves/block shell,
// with __launch_bounds__(256,4) for a 128-VGPR budget. R16's merged loop
// spilled (9.4 MB scratch) because its live set exceeded 64 regs; R15's (256,6)
// squeezed to 40 regs and re-read LDS in-loop. This is the untested combo:
// small-live-set dataflow + register headroom. Also drops the dead .w=0 store.

typedef _Float16 h2 __attribute__((ext_vector_type(2)));
typedef _Float16 h8 __attribute__((ext_vector_type(8)));

#define AH_STRIDE 36    // a-table row stride in dwords (32 data + 4 pad)
#define MW1_OFF  256    // ws offset: mw1 pairs, [24][48] dwords
#define MW2_OFF 1408    // ws offset: mw2 pairs, [24][48] dwords

union H8U { h8 v; h2 p[4]; unsigned u[4]; };

__device__ __forceinline__ h2 pkrtz(float a, float b) {
    return __builtin_bit_cast(h2, __builtin_amdgcn_cvt_pkrtz(a, b));
}
__device__ __forceinline__ h2 uash2(unsigned u) {
    return __builtin_bit_cast(h2, u);
}
__device__ __forceinline__ h2 hmax2(h2 a, h2 b) {
    return __builtin_elementwise_max(a, b);   // v_pk_max_f16
}

#if __has_builtin(__builtin_amdgcn_fdot2)
__device__ __forceinline__ float dot2acc(h2 a, h2 b, float c) {
    return __builtin_amdgcn_fdot2(a, b, c, false);
}
#else
__device__ __forceinline__ float dot2acc(h2 a, h2 b, float c) {
    float d;
    asm("v_dot2_f32_f16 %0, %1, %2, %3"
        : "=v"(d)
        : "v"(__builtin_bit_cast(int, a)), "v"(__builtin_bit_cast(int, b)), "v"(c));
    return d;
}
#endif

// sum across the 16-lane DPP row via row_ror 1,2,4,8 (all lanes get total)
__device__ __forceinline__ float dpp_add16(float x) {
    float s = x;
    int t;
    t = __builtin_amdgcn_update_dpp(0, __builtin_bit_cast(int, s), 0x121, 0xf, 0xf, false);
    s += __builtin_bit_cast(float, t);
    t = __builtin_amdgcn_update_dpp(0, __builtin_bit_cast(int, s), 0x122, 0xf, 0xf, false);
    s += __builtin_bit_cast(float, t);
    t = __builtin_amdgcn_update_dpp(0, __builtin_bit_cast(int, s), 0x124, 0xf, 0xf, false);
    s += __builtin_bit_cast(float, t);
    t = __builtin_amdgcn_update_dpp(0, __builtin_bit_cast(int, s), 0x128, 0xf, 0xf, false);
    s += __builtin_bit_cast(float, t);
    return s;
}

// ---- pre-kernel: pack f16-pair weight tables into workspace ----
__global__ void wpack(const float* __restrict__ pw2, const float* __restrict__ aw1,
                      const float* __restrict__ ab1, const float* __restrict__ aw2,
                      const float* __restrict__ mw1, const float* __restrict__ mw2,
                      unsigned* __restrict__ ws) {
    const int t = threadIdx.x;
    const float L2E = 1.44269504f;
    if (blockIdx.x == 0) {
        if (t < 96) {
            const int hp = t & 31, c = t >> 5;
            ws[c*32+hp] = __builtin_bit_cast(unsigned, pkrtz(pw2[(2*hp)*3+c], pw2[(2*hp+1)*3+c]));
        } else if (t < 114) {
            const int idx = t - 96, r = idx / 6, gp = idx % 6;
            ws[96+r*6+gp] = __builtin_bit_cast(unsigned, pkrtz(aw1[r*12+2*gp], aw1[r*12+2*gp+1]));
        } else if (t < 120) {
            const int gp = t - 114;
            ws[114+gp] = __builtin_bit_cast(unsigned, pkrtz(ab1[2*gp], ab1[2*gp+1]));
        } else if (t < 138) {
            const int idx = t - 120, gp = idx / 3, c = idx % 3;
            ws[120+gp*3+c] = __builtin_bit_cast(unsigned,
                pkrtz(aw2[(2*gp)*3+c] * L2E, aw2[(2*gp+1)*3+c] * L2E));
        }
    }
    // mw1/mw2 pair tables: 1152 entries each
    const int idx = blockIdx.x * 256 + t;
    if (idx < 1152) {
        const int cp = idx / 48, o = idx % 48;
        ws[MW1_OFF + idx] = __builtin_bit_cast(unsigned,
            pkrtz(mw1[(2*cp)*48+o], mw1[(2*cp+1)*48+o]));
        ws[MW2_OFF + idx] = __builtin_bit_cast(unsigned,
            pkrtz(mw2[(2*cp)*48+o], mw2[(2*cp+1)*48+o]));
    }
}

struct SmWave {
    float q4[64], k4[64], v4[64];      // 768 B
    float sa[48], h1[48];              // 384 B
    unsigned a1h[16 * AH_STRIDE];      // 2304 B
    unsigned a2h[16 * AH_STRIDE];      // 2304 B
};                                     // 5760 B/wave, 16B-aligned members

__global__ __launch_bounds__(256, 4) void pt_main(
    const float* __restrict__ data,     // (BG, 16, 3)
    const float* __restrict__ wqkv,     // (3, 9)
    const float* __restrict__ pw1,      // (3, 64)
    const float* __restrict__ pb1,      // (64)
    const float* __restrict__ pb2,      // (3)
    const float* __restrict__ ab2,      // (3)
    const float* __restrict__ mb1,      // (48)
    const float* __restrict__ mb2,      // (48)
    const float* __restrict__ mw3,      // (48, 1)
    const float* __restrict__ mb3,      // (1)
    const unsigned* __restrict__ wsp,   // packed f16-pair weights
    float* __restrict__ out)            // (BG)
{
    __shared__ __attribute__((aligned(16))) SmWave sm[4];

    const int tid = threadIdx.x;
    const int w   = tid >> 6;           // wave id within block
    const int ln  = tid & 63;           // lane within wave
    const int g   = blockIdx.x * 4 + w; // group handled by this wave
    SmWave& S = sm[w];

    // single data[] load for both phase-1 stages (same point p for 1a & 1b)
    const int p  = ln & 15;
    const float x0 = data[g*48 + p*3 + 0];
    const float x1 = data[g*48 + p*3 + 1];
    const float x2 = data[g*48 + p*3 + 2];

    // ---- phase 1a: qkv (lanes 0..47), stride-4 layout ----
    if (ln < 48) {
        const int sec = ln >> 4;
        float* dst = (sec == 0) ? S.q4 : (sec == 1) ? S.k4 : S.v4;
        #pragma unroll
        for (int c = 0; c < 3; ++c) {
            dst[p*4+c] = fmaf(x0, wqkv[0*9 + sec*3 + c],
                         fmaf(x1, wqkv[1*9 + sec*3 + c],
                         x2 * wqkv[2*9 + sec*3 + c]));
        }
        // .w lane of each float4 slot is never read; no zero store needed.
    }

    // ---- phase 1b: a-tables. lane -> point p, 16 hiddens at (ln>>4)*16 ----
    {
        const int qd = ln >> 4;
        const int hc = qd << 4;
        float s[16];
        #pragma unroll
        for (int c = 0; c < 16; ++c) {
            const int h = hc + c;
            s[c] = fmaf(x0, pw1[h], fmaf(x1, pw1[64+h], x2 * pw1[128+h]));
        }
        uint4 a1u0, a1u1, a2u0, a2u1;
        #pragma unroll
        for (int d = 0; d < 4; ++d) {
            const int c = d * 2;
            (&a1u0.x)[d] = __builtin_bit_cast(unsigned, pkrtz(s[c]   + pb1[hc+c],   s[c+1] + pb1[hc+c+1]));
            (&a1u1.x)[d] = __builtin_bit_cast(unsigned, pkrtz(s[8+c] + pb1[hc+8+c], s[9+c] + pb1[hc+9+c]));
            (&a2u0.x)[d] = __builtin_bit_cast(unsigned, pkrtz(s[c],   s[c+1]));
            (&a2u1.x)[d] = __builtin_bit_cast(unsigned, pkrtz(s[8+c], s[9+c]));
        }
        const int base = p * AH_STRIDE + (qd << 3);
        *(uint4*)&S.a1h[base]     = a1u0;
        *(uint4*)&S.a1h[base + 4] = a1u1;
        *(uint4*)&S.a2h[base]     = a2u0;
        *(uint4*)&S.a2h[base + 4] = a2u1;
    }
    __builtin_amdgcn_wave_barrier();   // order DS writes before phase-2 reads

    // ---- phase 2: 4 pairs per lane, processed 2+2. j=ln&15, i in {q,q+4,q+8,q+12} ----
    const int j = p, q = ln >> 4;
    const float4 kv = *(const float4*)&S.k4[j*4];
    const float4 vv = *(const float4*)&S.v4[j*4];
    const h2 z2 = {(_Float16)0, (_Float16)0};
    const float L2E = 1.44269504f;
    const float mb_0 = ab2[0] * L2E, mb_1 = ab2[1] * L2E, mb_2 = ab2[2] * L2E;

    // hoist the j-side a-table (shared by all 4 pairs): 8 x b128
    H8U ajr[8];
    #pragma unroll
    for (int cc = 0; cc < 8; ++cc)
        ajr[cc].v = *(const h8*)&S.a2h[j * AH_STRIDE + cc*4];

    #pragma unroll
    for (int half = 0; half < 2; ++half) {
        const int iA = q + 8*half, iB = iA + 4;

        float eA0 = pb2[0], eA1 = pb2[1], eA2 = pb2[2];
        float eB0 = pb2[0], eB1 = pb2[1], eB2 = pb2[2];
        #pragma unroll
        for (int cc = 0; cc < 8; ++cc) {
            H8U aiA, aiB;
            aiA.v = *(const h8*)&S.a1h[iA * AH_STRIDE + cc*4];
            aiB.v = *(const h8*)&S.a1h[iB * AH_STRIDE + cc*4];
            #pragma unroll
            for (int m = 0; m < 4; ++m) {
                const int hp = cc*4 + m;
                const h2 w0 = uash2(wsp[0*32+hp]);
                const h2 w1 = uash2(wsp[1*32+hp]);
                const h2 w2 = uash2(wsp[2*32+hp]);
                h2 rA = hmax2(aiA.p[m] - ajr[cc].p[m], z2);
                h2 rB = hmax2(aiB.p[m] - ajr[cc].p[m], z2);
                eA0 = dot2acc(rA, w0, eA0);
                eA1 = dot2acc(rA, w1, eA1);
                eA2 = dot2acc(rA, w2, eA2);
                eB0 = dot2acc(rB, w0, eB0);
                eB1 = dot2acc(rB, w1, eB1);
                eB2 = dot2acc(rB, w2, eB2);
            }
        }

        const float4 qA = *(const float4*)&S.q4[iA*4];
        const float4 qB = *(const float4*)&S.q4[iB*4];

        const float viA0 = vv.x + eA0, viA1 = vv.y + eA1, viA2 = vv.z + eA2;
        const float viB0 = vv.x + eB0, viB1 = vv.y + eB1, viB2 = vv.z + eB2;
        const float siA0 = qA.x - kv.x + eA0, siA1 = qA.y - kv.y + eA1, siA2 = qA.z - kv.z + eA2;
        const float siB0 = qB.x - kv.x + eB0, siB1 = qB.y - kv.y + eB1, siB2 = qB.z - kv.z + eB2;

        // attn-MLP in packed f16, both pairs (aw2/ab2 pre-scaled by L2E)
        const h2 sAx = pkrtz(siA0, siA0), sAy = pkrtz(siA1, siA1), sAz = pkrtz(siA2, siA2);
        const h2 sBx = pkrtz(siB0, siB0), sBy = pkrtz(siB1, siB1), sBz = pkrtz(siB2, siB2);
        float mA0 = mb_0, mA1 = mb_1, mA2 = mb_2;
        float mB0 = mb_0, mB1 = mb_1, mB2 = mb_2;
        #pragma unroll
        for (int gp = 0; gp < 6; ++gp) {
            const h2 b1p = uash2(wsp[114+gp]);
            const h2 u0 = uash2(wsp[96+0*6+gp]);
            const h2 u1 = uash2(wsp[96+1*6+gp]);
            const h2 u2 = uash2(wsp[96+2*6+gp]);
            const h2 v0 = uash2(wsp[120+gp*3+0]);
            const h2 v1 = uash2(wsp[120+gp*3+1]);
            const h2 v2 = uash2(wsp[120+gp*3+2]);
            h2 accA = b1p, accB = b1p;
            accA = __builtin_elementwise_fma(sAx, u0, accA);
            accA = __builtin_elementwise_fma(sAy, u1, accA);
            accA = __builtin_elementwise_fma(sAz, u2, accA);
            accB = __builtin_elementwise_fma(sBx, u0, accB);
            accB = __builtin_elementwise_fma(sBy, u1, accB);
            accB = __builtin_elementwise_fma(sBz, u2, accB);
            h2 hA = hmax2(accA, z2), hB = hmax2(accB, z2);
            mA0 = dot2acc(hA, v0, mA0);
            mA1 = dot2acc(hA, v1, mA1);
            mA2 = dot2acc(hA, v2, mA2);
            mB0 = dot2acc(hB, v0, mB0);
            mB1 = dot2acc(hB, v1, mB1);
            mB2 = dot2acc(hB, v2, mB2);
        }

        // softmax over j (DPP row sums; exponents already in log2 domain)
        const float pA0 = __builtin_amdgcn_exp2f(mA0);
        const float pA1 = __builtin_amdgcn_exp2f(mA1);
        const float pA2 = __builtin_amdgcn_exp2f(mA2);
        const float pB0 = __builtin_amdgcn_exp2f(mB0);
        const float pB1 = __builtin_amdgcn_exp2f(mB1);
        const float pB2 = __builtin_amdgcn_exp2f(mB2);

        const float nA0 = dpp_add16(pA0 * viA0);
        const float nA1 = dpp_add16(pA1 * viA1);
        const float nA2 = dpp_add16(pA2 * viA2);
        const float dA0 = dpp_add16(pA0);
        const float dA1 = dpp_add16(pA1);
        const float dA2 = dpp_add16(pA2);
        const float nB0 = dpp_add16(pB0 * viB0);
        const float nB1 = dpp_add16(pB1 * viB1);
        const float nB2 = dpp_add16(pB2 * viB2);
        const float dB0 = dpp_add16(pB0);
        const float dB1 = dpp_add16(pB1);
        const float dB2 = dpp_add16(pB2);

        if (j == 0) {
            S.sa[iA*3+0] = nA0 * __builtin_amdgcn_rcpf(dA0);
            S.sa[iA*3+1] = nA1 * __builtin_amdgcn_rcpf(dA1);
            S.sa[iA*3+2] = nA2 * __builtin_amdgcn_rcpf(dA2);
            S.sa[iB*3+0] = nB0 * __builtin_amdgcn_rcpf(dB0);
            S.sa[iB*3+1] = nB1 * __builtin_amdgcn_rcpf(dB1);
            S.sa[iB*3+2] = nB2 * __builtin_amdgcn_rcpf(dB2);
        }
    }
    __builtin_amdgcn_wave_barrier();   // s_sa writes before tail reads

    // ---- phase 3: MLP 48->48->48->1 (lanes 0..47), f16-pair weights ----
    if (ln < 48) {
        const int o = ln;
        float a0 = 0.f, a1 = 0.f;
        #pragma unroll
        for (int c = 0; c < 48; c += 4) {
            const float4 sa = *(const float4*)&S.sa[c];   // broadcast read
            const h2 pa = pkrtz(sa.x, sa.y);
            const h2 pb = pkrtz(sa.z, sa.w);
            a0 = dot2acc(pa, uash2(wsp[MW1_OFF + (c>>1)*48 + o]), a0);
            a1 = dot2acc(pb, uash2(wsp[MW1_OFF + ((c>>1)+1)*48 + o]), a1);
        }
        S.h1[o] = fmaxf(a0 + a1 + mb1[o], 0.0f);
        __builtin_amdgcn_wave_barrier();   // same-wave LDS handoff
        float b0 = 0.f, b1 = 0.f;
        #pragma unroll
        for (int c = 0; c < 48; c += 4) {
            const float4 hh = *(const float4*)&S.h1[c];
            const h2 pa = pkrtz(hh.x, hh.y);
            const h2 pb = pkrtz(hh.z, hh.w);
            b0 = dot2acc(pa, uash2(wsp[MW2_OFF + (c>>1)*48 + o]), b0);
            b1 = dot2acc(pb, uash2(wsp[MW2_OFF + ((c>>1)+1)*48 + o]), b1);
        }
        const float h2v = fmaxf(b0 + b1 + mb2[o], 0.0f);
        const float fv = h2v * mw3[o];
        const float r = dpp_add16(fv);     // row sums in lanes 0,16,32
        const int ri = __builtin_bit_cast(int, r);
        const float tot =
            __builtin_bit_cast(float, __builtin_amdgcn_readlane(ri, 0)) +
            __builtin_bit_cast(float, __builtin_amdgcn_readlane(ri, 16)) +
            __builtin_bit_cast(float, __builtin_amdgcn_readlane(ri, 32));
        if (o == 0) out[g] = tot + mb3[0];
    }
}

extern "C" void kernel_launch(void* const* d_in, const int* in_sizes, int n_in,
                              void* d_out, int out_size, void* d_ws, size_t ws_size,
                              hipStream_t stream) {
    const float* data = (const float*)d_in[1];
    unsigned* ws = (unsigned*)d_ws;
    const int groups = out_size;  // B*G = 16384

    wpack<<<5, 256, 0, stream>>>(
        (const float*)d_in[5],   // pw2
        (const float*)d_in[7],   // aw1
        (const float*)d_in[8],   // ab1
        (const float*)d_in[9],   // aw2
        (const float*)d_in[11],  // mw1
        (const float*)d_in[13],  // mw2
        ws);

    pt_main<<<groups / 4, 256, 0, stream>>>(
        data,
        (const float*)d_in[2],   // wqkv
        (const float*)d_in[3],   // pw1
        (const float*)d_in[4],   // pb1
        (const float*)d_in[6],   // pb2
        (const float*)d_in[10],  // ab2
        (const float*)d_in[12],  // mb1
        (const float*)d_in[14],  // mb2
        (const float*)d_in[15],  // mw3
        (const float*)d_in[16],  // mb3
        ws,
        (float*)d_out);
}

// Round 6
// 127.310 us; speedup vs baseline: 1.0831x; 1.0660x over previous
//
#include <hip/hip_runtime.h>

// Point-transformer block. R19 = R18 resubmitted verbatim (previous round's
// bench died with "MI355X container failed twice" -- infra, no counters, no
// pass/fail signal; source re-audited for OOB/alignment/hang: clean).
// R18 = R15 shell (4 groups/block, 4 autonomous waves, (256,6), proven
// 54.5us) with the rel-emb projection moved to MFMA. Per group,
// e(i,j,c) = relu(a1[i]-a2[j]) @ pos_w2 is 16 matmuls (16j x 64h)@(64h x 3c).
// Layout trick: A = pos_w2 with row r holding column r&3 (rows r&3==3 zero),
// B[k][j] = relu(a1[t][k]-a2[j][k]). Then D row=(l>>4)*4+reg, col=l&15 gives
// every lane e(t, j=l&15, c=reg) in regs 0..2 -- exactly the downstream
// per-pair layout. C-in carries pb2 (free bias). Lane keeps t where t&3==q.
// Replaces 640 VALU/lane (e-loop) with ~336 VALU + 32 MFMA on the idle
// matrix pipe. Everything else bit-identical to R15.

typedef _Float16 h2 __attribute__((ext_vector_type(2)));
typedef _Float16 h8 __attribute__((ext_vector_type(8)));
typedef float f32x4 __attribute__((ext_vector_type(4)));

#define AH_STRIDE 36    // a-table row stride in dwords (32 data + 4 pad)
#define MW1_OFF  256    // ws offset: mw1 pairs, [24][48] dwords
#define MW2_OFF 1408    // ws offset: mw2 pairs, [24][48] dwords
#define AW2T_OFF 2560   // ws offset: MFMA A-frag table for pos_w2, [2 chunks][64 lanes][4 dwords]

union H8U { h8 v; h2 p[4]; unsigned u[4]; };

__device__ __forceinline__ h2 pkrtz(float a, float b) {
    return __builtin_bit_cast(h2, __builtin_amdgcn_cvt_pkrtz(a, b));
}
__device__ __forceinline__ h2 uash2(unsigned u) {
    return __builtin_bit_cast(h2, u);
}
__device__ __forceinline__ h2 hmax2(h2 a, h2 b) {
    return __builtin_elementwise_max(a, b);   // v_pk_max_f16
}

#if __has_builtin(__builtin_amdgcn_fdot2)
__device__ __forceinline__ float dot2acc(h2 a, h2 b, float c) {
    return __builtin_amdgcn_fdot2(a, b, c, false);
}
#else
__device__ __forceinline__ float dot2acc(h2 a, h2 b, float c) {
    float d;
    asm("v_dot2_f32_f16 %0, %1, %2, %3"
        : "=v"(d)
        : "v"(__builtin_bit_cast(int, a)), "v"(__builtin_bit_cast(int, b)), "v"(c));
    return d;
}
#endif

// sum across the 16-lane DPP row via row_ror 1,2,4,8 (all lanes get total)
__device__ __forceinline__ float dpp_add16(float x) {
    float s = x;
    int t;
    t = __builtin_amdgcn_update_dpp(0, __builtin_bit_cast(int, s), 0x121, 0xf, 0xf, false);
    s += __builtin_bit_cast(float, t);
    t = __builtin_amdgcn_update_dpp(0, __builtin_bit_cast(int, s), 0x122, 0xf, 0xf, false);
    s += __builtin_bit_cast(float, t);
    t = __builtin_amdgcn_update_dpp(0, __builtin_bit_cast(int, s), 0x124, 0xf, 0xf, false);
    s += __builtin_bit_cast(float, t);
    t = __builtin_amdgcn_update_dpp(0, __builtin_bit_cast(int, s), 0x128, 0xf, 0xf, false);
    s += __builtin_bit_cast(float, t);
    return s;
}

// ---- pre-kernel: pack f16-pair weight tables into workspace ----
__global__ void wpack(const float* __restrict__ pw2, const float* __restrict__ aw1,
                      const float* __restrict__ ab1, const float* __restrict__ aw2,
                      const float* __restrict__ mw1, const float* __restrict__ mw2,
                      unsigned* __restrict__ ws) {
    const int t = threadIdx.x;
    const float L2E = 1.44269504f;
    if (blockIdx.x == 0) {
        if (t < 96) {
            const int hp = t & 31, c = t >> 5;
            ws[c*32+hp] = __builtin_bit_cast(unsigned, pkrtz(pw2[(2*hp)*3+c], pw2[(2*hp+1)*3+c]));
        } else if (t < 114) {
            const int idx = t - 96, r = idx / 6, gp = idx % 6;
            ws[96+r*6+gp] = __builtin_bit_cast(unsigned, pkrtz(aw1[r*12+2*gp], aw1[r*12+2*gp+1]));
        } else if (t < 120) {
            const int gp = t - 114;
            ws[114+gp] = __builtin_bit_cast(unsigned, pkrtz(ab1[2*gp], ab1[2*gp+1]));
        } else if (t < 138) {
            const int idx = t - 120, gp = idx / 3, c = idx % 3;
            ws[120+gp*3+c] = __builtin_bit_cast(unsigned,
                pkrtz(aw2[(2*gp)*3+c] * L2E, aw2[(2*gp+1)*3+c] * L2E));
        }
    }
    const int idx = blockIdx.x * 256 + t;
    // mw1/mw2 pair tables: 1152 entries each
    if (idx < 1152) {
        const int cp = idx / 48, o = idx % 48;
        ws[MW1_OFF + idx] = __builtin_bit_cast(unsigned,
            pkrtz(mw1[(2*cp)*48+o], mw1[(2*cp+1)*48+o]));
        ws[MW2_OFF + idx] = __builtin_bit_cast(unsigned,
            pkrtz(mw2[(2*cp)*48+o], mw2[(2*cp+1)*48+o]));
    }
    // MFMA A-frag table: A[row][k] = (row&3)<3 ? pos_w2[k][row&3] : 0
    // lane l holds A[l&15][(l>>4)*8 + e], e=0..7, per 32-K chunk; stored as
    // f16 pairs: ws[AW2T_OFF + ch*256 + l*4 + d] = (k=2d, k=2d+1)
    if (idx < 512) {
        const int ch = idx >> 8, rem = idx & 255;
        const int l = rem >> 2, d = rem & 3;
        const int c = (l & 15) & 3;
        const bool valid = c < 3;
        const int h0 = ((l >> 4) * 8) + 2*d + 32*ch;
        const float v0 = valid ? pw2[h0*3 + c] : 0.0f;
        const float v1 = valid ? pw2[(h0+1)*3 + c] : 0.0f;
        ws[AW2T_OFF + idx] = __builtin_bit_cast(unsigned, pkrtz(v0, v1));
    }
}

struct SmWave {
    float q4[64], k4[64], v4[64];      // 768 B
    float sa[48], h1[48];              // 384 B
    unsigned a1h[16 * AH_STRIDE];      // 2304 B
    unsigned a2h[16 * AH_STRIDE];      // 2304 B
};                                     // 5760 B/wave, 16B-aligned members

__global__ __launch_bounds__(256, 6) void pt_main(
    const float* __restrict__ data,     // (BG, 16, 3)
    const float* __restrict__ wqkv,     // (3, 9)
    const float* __restrict__ pw1,      // (3, 64)
    const float* __restrict__ pb1,      // (64)
    const float* __restrict__ pb2,      // (3)
    const float* __restrict__ ab2,      // (3)
    const float* __restrict__ mb1,      // (48)
    const float* __restrict__ mb2,      // (48)
    const float* __restrict__ mw3,      // (48, 1)
    const float* __restrict__ mb3,      // (1)
    const unsigned* __restrict__ wsp,   // packed f16-pair weights
    float* __restrict__ out)            // (BG)
{
    __shared__ __attribute__((aligned(16))) SmWave sm[4];

    const int tid = threadIdx.x;
    const int w   = tid >> 6;           // wave id within block
    const int ln  = tid & 63;           // lane within wave
    const int g   = blockIdx.x * 4 + w; // group handled by this wave
    SmWave& S = sm[w];

    // single data[] load for both phase-1 stages (same point p for 1a & 1b)
    const int p  = ln & 15;
    const float x0 = data[g*48 + p*3 + 0];
    const float x1 = data[g*48 + p*3 + 1];
    const float x2 = data[g*48 + p*3 + 2];

    // ---- phase 1a: qkv (lanes 0..47), stride-4 layout ----
    if (ln < 48) {
        const int sec = ln >> 4;
        float* dst = (sec == 0) ? S.q4 : (sec == 1) ? S.k4 : S.v4;
        #pragma unroll
        for (int c = 0; c < 3; ++c) {
            dst[p*4+c] = fmaf(x0, wqkv[0*9 + sec*3 + c],
                         fmaf(x1, wqkv[1*9 + sec*3 + c],
                         x2 * wqkv[2*9 + sec*3 + c]));
        }
        dst[p*4+3] = 0.0f;
    }

    // ---- phase 1b: a-tables. lane -> point p, 16 hiddens at (ln>>4)*16 ----
    {
        const int qd = ln >> 4;
        const int hc = qd << 4;
        float s[16];
        #pragma unroll
        for (int c = 0; c < 16; ++c) {
            const int h = hc + c;
            s[c] = fmaf(x0, pw1[h], fmaf(x1, pw1[64+h], x2 * pw1[128+h]));
        }
        uint4 a1u0, a1u1, a2u0, a2u1;
        #pragma unroll
        for (int d = 0; d < 4; ++d) {
            const int c = d * 2;
            (&a1u0.x)[d] = __builtin_bit_cast(unsigned, pkrtz(s[c]   + pb1[hc+c],   s[c+1] + pb1[hc+c+1]));
            (&a1u1.x)[d] = __builtin_bit_cast(unsigned, pkrtz(s[8+c] + pb1[hc+8+c], s[9+c] + pb1[hc+9+c]));
            (&a2u0.x)[d] = __builtin_bit_cast(unsigned, pkrtz(s[c],   s[c+1]));
            (&a2u1.x)[d] = __builtin_bit_cast(unsigned, pkrtz(s[8+c], s[9+c]));
        }
        const int base = p * AH_STRIDE + (qd << 3);
        *(uint4*)&S.a1h[base]     = a1u0;
        *(uint4*)&S.a1h[base + 4] = a1u1;
        *(uint4*)&S.a2h[base]     = a2u0;
        *(uint4*)&S.a2h[base + 4] = a2u1;
    }
    __builtin_amdgcn_wave_barrier();   // order DS writes before phase-2 reads

    // ---- phase 2: j = ln&15, q = ln>>4; lane owns pairs (i = q+4s, j) ----
    const int j = p, q = ln >> 4;
    const float4 kv = *(const float4*)&S.k4[j*4];
    const float4 vv = *(const float4*)&S.v4[j*4];
    const h2 z2 = {(_Float16)0, (_Float16)0};
    const float L2E = 1.44269504f;
    const float mb_0 = ab2[0] * L2E, mb_1 = ab2[1] * L2E, mb_2 = ab2[2] * L2E;

    // ---- phase 2a: rel-emb projection via MFMA ----
    // hoisted A-frags (pos_w2 c-replicated table) and this lane's a2 k-slice
    H8U af0, af1;
    *(uint4*)&af0 = *(const uint4*)&wsp[AW2T_OFF + ln*4];
    *(uint4*)&af1 = *(const uint4*)&wsp[AW2T_OFF + 256 + ln*4];
    H8U b2c0, b2c1;
    b2c0.v = *(const h8*)&S.a2h[j * AH_STRIDE + q*4];
    b2c1.v = *(const h8*)&S.a2h[j * AH_STRIDE + q*4 + 16];

    const f32x4 pb2v = {pb2[0], pb2[1], pb2[2], 0.0f};
    float e[4][3];
    #pragma unroll
    for (int s = 0; s < 4; ++s) { e[s][0] = 0.f; e[s][1] = 0.f; e[s][2] = 0.f; }

    #pragma unroll
    for (int t = 0; t < 16; ++t) {
        H8U r0, r1, d0, d1;
        r0.v = *(const h8*)&S.a1h[t * AH_STRIDE + q*4];
        r1.v = *(const h8*)&S.a1h[t * AH_STRIDE + q*4 + 16];
        #pragma unroll
        for (int m = 0; m < 4; ++m) {
            d0.p[m] = hmax2(r0.p[m] - b2c0.p[m], z2);
            d1.p[m] = hmax2(r1.p[m] - b2c1.p[m], z2);
        }
        f32x4 acc = __builtin_amdgcn_mfma_f32_16x16x32_f16(af0.v, d0.v, pb2v, 0, 0, 0);
        acc = __builtin_amdgcn_mfma_f32_16x16x32_f16(af1.v, d1.v, acc, 0, 0, 0);
        const int s = t >> 2;
        const bool keep = (q == (t & 3));
        e[s][0] = keep ? acc[0] : e[s][0];
        e[s][1] = keep ? acc[1] : e[s][1];
        e[s][2] = keep ? acc[2] : e[s][2];
    }

    // ---- phase 2b: attn-MLP + softmax, two halves (proven R13 dataflow) ----
    #pragma unroll
    for (int half = 0; half < 2; ++half) {
        const int iA = q + 8*half, iB = iA + 4;
        const int ha = 2*half, hb = 2*half + 1;

        const float eA0 = e[ha][0], eA1 = e[ha][1], eA2 = e[ha][2];
        const float eB0 = e[hb][0], eB1 = e[hb][1], eB2 = e[hb][2];

        const float4 qA = *(const float4*)&S.q4[iA*4];
        const float4 qB = *(const float4*)&S.q4[iB*4];

        const float viA0 = vv.x + eA0, viA1 = vv.y + eA1, viA2 = vv.z + eA2;
        const float viB0 = vv.x + eB0, viB1 = vv.y + eB1, viB2 = vv.z + eB2;
        const float siA0 = qA.x - kv.x + eA0, siA1 = qA.y - kv.y + eA1, siA2 = qA.z - kv.z + eA2;
        const float siB0 = qB.x - kv.x + eB0, siB1 = qB.y - kv.y + eB1, siB2 = qB.z - kv.z + eB2;

        // attn-MLP in packed f16, both pairs (aw2/ab2 pre-scaled by L2E)
        const h2 sAx = pkrtz(siA0, siA0), sAy = pkrtz(siA1, siA1), sAz = pkrtz(siA2, siA2);
        const h2 sBx = pkrtz(siB0, siB0), sBy = pkrtz(siB1, siB1), sBz = pkrtz(siB2, siB2);
        float mA0 = mb_0, mA1 = mb_1, mA2 = mb_2;
        float mB0 = mb_0, mB1 = mb_1, mB2 = mb_2;
        #pragma unroll
        for (int gp = 0; gp < 6; ++gp) {
            const h2 b1p = uash2(wsp[114+gp]);
            const h2 u0 = uash2(wsp[96+0*6+gp]);
            const h2 u1 = uash2(wsp[96+1*6+gp]);
            const h2 u2 = uash2(wsp[96+2*6+gp]);
            const h2 v0 = uash2(wsp[120+gp*3+0]);
            const h2 v1 = uash2(wsp[120+gp*3+1]);
            const h2 v2 = uash2(wsp[120+gp*3+2]);
            h2 accA = b1p, accB = b1p;
            accA = __builtin_elementwise_fma(sAx, u0, accA);
            accA = __builtin_elementwise_fma(sAy, u1, accA);
            accA = __builtin_elementwise_fma(sAz, u2, accA);
            accB = __builtin_elementwise_fma(sBx, u0, accB);
            accB = __builtin_elementwise_fma(sBy, u1, accB);
            accB = __builtin_elementwise_fma(sBz, u2, accB);
            h2 hA = hmax2(accA, z2), hB = hmax2(accB, z2);
            mA0 = dot2acc(hA, v0, mA0);
            mA1 = dot2acc(hA, v1, mA1);
            mA2 = dot2acc(hA, v2, mA2);
            mB0 = dot2acc(hB, v0, mB0);
            mB1 = dot2acc(hB, v1, mB1);
            mB2 = dot2acc(hB, v2, mB2);
        }

        // softmax over j (DPP row sums; exponents already in log2 domain)
        const float pA0 = __builtin_amdgcn_exp2f(mA0);
        const float pA1 = __builtin_amdgcn_exp2f(mA1);
        const float pA2 = __builtin_amdgcn_exp2f(mA2);
        const float pB0 = __builtin_amdgcn_exp2f(mB0);
        const float pB1 = __builtin_amdgcn_exp2f(mB1);
        const float pB2 = __builtin_amdgcn_exp2f(mB2);

        const float nA0 = dpp_add16(pA0 * viA0);
        const float nA1 = dpp_add16(pA1 * viA1);
        const float nA2 = dpp_add16(pA2 * viA2);
        const float dA0 = dpp_add16(pA0);
        const float dA1 = dpp_add16(pA1);
        const float dA2 = dpp_add16(pA2);
        const float nB0 = dpp_add16(pB0 * viB0);
        const float nB1 = dpp_add16(pB1 * viB1);
        const float nB2 = dpp_add16(pB2 * viB2);
        const float dB0 = dpp_add16(pB0);
        const float dB1 = dpp_add16(pB1);
        const float dB2 = dpp_add16(pB2);

        if (j == 0) {
            S.sa[iA*3+0] = nA0 * __builtin_amdgcn_rcpf(dA0);
            S.sa[iA*3+1] = nA1 * __builtin_amdgcn_rcpf(dA1);
            S.sa[iA*3+2] = nA2 * __builtin_amdgcn_rcpf(dA2);
            S.sa[iB*3+0] = nB0 * __builtin_amdgcn_rcpf(dB0);
            S.sa[iB*3+1] = nB1 * __builtin_amdgcn_rcpf(dB1);
            S.sa[iB*3+2] = nB2 * __builtin_amdgcn_rcpf(dB2);
        }
    }
    __builtin_amdgcn_wave_barrier();   // s_sa writes before tail reads

    // ---- phase 3: MLP 48->48->48->1 (lanes 0..47), f16-pair weights ----
    if (ln < 48) {
        const int o = ln;
        float a0 = 0.f, a1 = 0.f;
        #pragma unroll
        for (int c = 0; c < 48; c += 4) {
            const float4 sa = *(const float4*)&S.sa[c];   // broadcast read
            const h2 pa = pkrtz(sa.x, sa.y);
            const h2 pb = pkrtz(sa.z, sa.w);
            a0 = dot2acc(pa, uash2(wsp[MW1_OFF + (c>>1)*48 + o]), a0);
            a1 = dot2acc(pb, uash2(wsp[MW1_OFF + ((c>>1)+1)*48 + o]), a1);
        }
        S.h1[o] = fmaxf(a0 + a1 + mb1[o], 0.0f);
        __builtin_amdgcn_wave_barrier();   // same-wave LDS handoff
        float b0 = 0.f, b1 = 0.f;
        #pragma unroll
        for (int c = 0; c < 48; c += 4) {
            const float4 hh = *(const float4*)&S.h1[c];
            const h2 pa = pkrtz(hh.x, hh.y);
            const h2 pb = pkrtz(hh.z, hh.w);
            b0 = dot2acc(pa, uash2(wsp[MW2_OFF + (c>>1)*48 + o]), b0);
            b1 = dot2acc(pb, uash2(wsp[MW2_OFF + ((c>>1)+1)*48 + o]), b1);
        }
        const float h2v = fmaxf(b0 + b1 + mb2[o], 0.0f);
        const float fv = h2v * mw3[o];
        const float r = dpp_add16(fv);     // row sums in lanes 0,16,32
        const int ri = __builtin_bit_cast(int, r);
        const float tot =
            __builtin_bit_cast(float, __builtin_amdgcn_readlane(ri, 0)) +
            __builtin_bit_cast(float, __builtin_amdgcn_readlane(ri, 16)) +
            __builtin_bit_cast(float, __builtin_amdgcn_readlane(ri, 32));
        if (o == 0) out[g] = tot + mb3[0];
    }
}

extern "C" void kernel_launch(void* const* d_in, const int* in_sizes, int n_in,
                              void* d_out, int out_size, void* d_ws, size_t ws_size,
                              hipStream_t stream) {
    const float* data = (const float*)d_in[1];
    unsigned* ws = (unsigned*)d_ws;
    const int groups = out_size;  // B*G = 16384

    wpack<<<5, 256, 0, stream>>>(
        (const float*)d_in[5],   // pw2
        (const float*)d_in[7],   // aw1
        (const float*)d_in[8],   // ab1
        (const float*)d_in[9],   // aw2
        (const float*)d_in[11],  // mw1
        (const float*)d_in[13],  // mw2
        ws);

    pt_main<<<groups / 4, 256, 0, stream>>>(
        data,
        (const float*)d_in[2],   // wqkv
        (const float*)d_in[3],   // pw1
        (const float*)d_in[4],   // pb1
        (const float*)d_in[6],   // pb2
        (const float*)d_in[10],  // ab2
        (const float*)d_in[12],  // mb1
        (const float*)d_in[14],  // mb2
        (const float*)d_in[15],  // mw3
        (const float*)d_in[16],  // mb3
        ws,
        (float*)d_out);
}